// Round 2
// baseline (2897.245 us; speedup 1.0000x reference)
//
#include <hip/hip_runtime.h>
#include <math.h>

#define N_NODES 10000
#define N_EDGES 320000
#define HID 64
#define EDGE_IN 131   /* 2*64 + 1 + 2 */
#define N_LAYERS 4

__device__ __forceinline__ float silu_f(float x) {
    return x * (1.0f / (1.0f + __expf(-x)));
}

// ---------------- init: copy x,v + normalized init vel ----------------
__global__ void init_kernel(const float* __restrict__ loc, const float* __restrict__ vel,
                            float* __restrict__ x, float* __restrict__ v, float* __restrict__ iv) {
    int i = blockIdx.x * blockDim.x + threadIdx.x;
    if (i >= N_NODES) return;
    float v0 = vel[3*i], v1 = vel[3*i+1], v2 = vel[3*i+2];
    float nrm = sqrtf(v0*v0 + v1*v1 + v2*v2) + 1e-8f;
    x[3*i] = loc[3*i]; x[3*i+1] = loc[3*i+1]; x[3*i+2] = loc[3*i+2];
    v[3*i] = v0; v[3*i+1] = v1; v[3*i+2] = v2;
    iv[3*i] = v0/nrm; iv[3*i+1] = v1/nrm; iv[3*i+2] = v2/nrm;
}

// ---------------- embedding: h0 = his @ emb_w + emb_b ----------------
__global__ __launch_bounds__(64) void embed_kernel(const float* __restrict__ his,
                                                   const float* __restrict__ w,
                                                   const float* __restrict__ b,
                                                   float* __restrict__ h0) {
    int i = blockIdx.x, l = threadIdx.x;
    float acc = b[l];
    #pragma unroll
    for (int k = 0; k < 4; ++k) acc += his[i*4+k] * w[k*HID+l];
    h0[i*HID+l] = acc;
}

// ---------------- CSR build ----------------
__global__ void count_kernel(const int* __restrict__ erow, int* __restrict__ counts) {
    int e = blockIdx.x * blockDim.x + threadIdx.x;
    if (e < N_EDGES) atomicAdd(&counts[erow[e]], 1);
}

__global__ __launch_bounds__(1024) void scan_kernel(const int* __restrict__ counts,
                                                    int* __restrict__ offs) {
    __shared__ int sd[1024];
    __shared__ int running;
    if (threadIdx.x == 0) { running = 0; offs[0] = 0; }
    __syncthreads();
    for (int base = 0; base < N_NODES; base += 1024) {
        int i = base + threadIdx.x;
        int val = (i < N_NODES) ? counts[i] : 0;
        sd[threadIdx.x] = val;
        __syncthreads();
        for (int d = 1; d < 1024; d <<= 1) {
            int tmp = (threadIdx.x >= d) ? sd[threadIdx.x - d] : 0;
            __syncthreads();
            sd[threadIdx.x] += tmp;
            __syncthreads();
        }
        if (i < N_NODES) offs[i+1] = running + sd[threadIdx.x];
        __syncthreads();
        if (threadIdx.x == 0) running += sd[1023];
        __syncthreads();
    }
}

__global__ void scatter_kernel(const int* __restrict__ erow, const int* __restrict__ offs,
                               int* __restrict__ cursor, int* __restrict__ elist) {
    int e = blockIdx.x * blockDim.x + threadIdx.x;
    if (e < N_EDGES) {
        int r = erow[e];
        int p = atomicAdd(&cursor[r], 1);
        elist[offs[r] + p] = e;
    }
}

// ---------------- fused edge kernel ----------------
// Per edge: radial, edge MLP (131->64 silu, 64->64 silu), coord gate
// (64->64 silu, dot coord_w2). Outputs ef[E,64] and cg[E,3]=coord_diff*gate.
__global__ __launch_bounds__(256) void edge_kernel(
    const float* __restrict__ h, const float* __restrict__ x,
    const int* __restrict__ erow, const int* __restrict__ ecol,
    const float* __restrict__ eattr,
    const float* __restrict__ ew1, const float* __restrict__ eb1,
    const float* __restrict__ ew2, const float* __restrict__ eb2,
    const float* __restrict__ cw1, const float* __restrict__ cb1,
    const float* __restrict__ cw2,
    float* __restrict__ ef_out, float* __restrict__ cg_out)
{
    __shared__ float sW1[EDGE_IN*HID];   // 33.5 KB
    __shared__ float sW2[HID*HID];       // 16 KB
    __shared__ float sC1[HID*HID];       // 16 KB
    __shared__ float sB1[HID], sB2[HID], sCB1[HID], sCW2[HID];
    __shared__ float stage[4][3*HID];    // per-wave scratch

    for (int i = threadIdx.x; i < EDGE_IN*HID; i += 256) sW1[i] = ew1[i];
    for (int i = threadIdx.x; i < HID*HID; i += 256) { sW2[i] = ew2[i]; sC1[i] = cw1[i]; }
    if (threadIdx.x < HID) {
        sB1[threadIdx.x]  = eb1[threadIdx.x];
        sB2[threadIdx.x]  = eb2[threadIdx.x];
        sCB1[threadIdx.x] = cb1[threadIdx.x];
        sCW2[threadIdx.x] = cw2[threadIdx.x];
    }
    __syncthreads();

    const int wave = threadIdx.x >> 6;
    const int lane = threadIdx.x & 63;
    float* st = stage[wave];
    const int nwaves = gridDim.x * 4;
    const int iters = (N_EDGES + nwaves - 1) / nwaves;
    int e = blockIdx.x * 4 + wave;

    for (int it = 0; it < iters; ++it, e += nwaves) {
        const bool valid = (e < N_EDGES);
        const int ee = valid ? e : 0;
        const int r = erow[ee], c = ecol[ee];
        const float d0 = x[3*r]   - x[3*c];
        const float d1 = x[3*r+1] - x[3*c+1];
        const float d2 = x[3*r+2] - x[3*c+2];
        const float radial = d0*d0 + d1*d1 + d2*d2;
        const float a0 = eattr[2*ee], a1 = eattr[2*ee+1];
        st[lane]       = h[(size_t)r*HID + lane];
        st[HID + lane] = h[(size_t)c*HID + lane];
        __syncthreads();

        float acc = sB1[lane] + radial * sW1[128*HID + lane]
                  + a0 * sW1[129*HID + lane] + a1 * sW1[130*HID + lane];
        #pragma unroll 8
        for (int k = 0; k < 2*HID; ++k) acc += st[k] * sW1[k*HID + lane];
        float f1 = silu_f(acc);
        st[2*HID + lane] = f1;
        __syncthreads();

        float acc2 = sB2[lane];
        #pragma unroll 8
        for (int k = 0; k < HID; ++k) acc2 += st[2*HID + k] * sW2[k*HID + lane];
        float ef = silu_f(acc2);
        if (valid) ef_out[(size_t)e*HID + lane] = ef;
        st[lane] = ef;                 // overwrite h_row slot (done with it)
        __syncthreads();

        float g = sCB1[lane];
        #pragma unroll 8
        for (int k = 0; k < HID; ++k) g += st[k] * sC1[k*HID + lane];
        g = silu_f(g) * sCW2[lane];
        #pragma unroll
        for (int d = 32; d > 0; d >>= 1) g += __shfl_xor(g, d, 64);
        if (valid && lane < 3) {
            float dd = (lane == 0) ? d0 : ((lane == 1) ? d1 : d2);
            cg_out[(size_t)e*3 + lane] = dd * g;
        }
        __syncthreads();
    }
}

// ---------------- node kernel: aggregate + vel/coord + node MLP ----------------
__global__ __launch_bounds__(64) void node_kernel(
    const float* __restrict__ h_in, float* __restrict__ h_out,
    float* __restrict__ x, float* __restrict__ v, const float* __restrict__ iv,
    const float* __restrict__ ef, const float* __restrict__ cg,
    const int* __restrict__ offs, const int* __restrict__ elist,
    const float* __restrict__ nw1, const float* __restrict__ nb1,
    const float* __restrict__ nw2, const float* __restrict__ nb2,
    const float* __restrict__ vw1, const float* __restrict__ vb1,
    const float* __restrict__ vw2, const float* __restrict__ vb2)
{
    const int i = blockIdx.x, l = threadIdx.x;
    __shared__ float sh[HID], sagg[HID], st1[HID];
    const float hl = h_in[(size_t)i*HID + l];
    sh[l] = hl;
    const int s = offs[i], t = offs[i+1];
    float aggl = 0.f, accl = 0.f;
    for (int p = s; p < t; ++p) {
        const int e = elist[p];
        aggl += ef[(size_t)e*HID + l];
        if (l < 3) accl += cg[(size_t)e*3 + l];
    }
    sagg[l] = aggl;
    __syncthreads();

    // phi = silu(h @ vw1 + vb1) @ vw2 + vb2
    float a = vb1[l];
    #pragma unroll 8
    for (int k = 0; k < HID; ++k) a += sh[k] * vw1[k*HID + l];
    float pl = silu_f(a) * vw2[l];
    #pragma unroll
    for (int d = 32; d > 0; d >>= 1) pl += __shfl_xor(pl, d, 64);
    const float phi = pl + vb2[0];

    // node MLP: silu([h, agg] @ nw1 + nb1) @ nw2 + nb2, residual add
    float b = nb1[l];
    #pragma unroll 8
    for (int k = 0; k < HID; ++k) b += sh[k]   * nw1[k*HID + l];
    #pragma unroll 8
    for (int k = 0; k < HID; ++k) b += sagg[k] * nw1[(HID+k)*HID + l];
    b = silu_f(b);
    st1[l] = b;
    __syncthreads();
    float cacc = nb2[l];
    #pragma unroll 8
    for (int k = 0; k < HID; ++k) cacc += st1[k] * nw2[k*HID + l];
    h_out[(size_t)i*HID + l] = hl + cacc;

    if (l < 3) {
        const int cnt = t - s;
        const float acc = accl / (float)(cnt > 0 ? cnt : 1);
        const float vn = v[3*i + l] + acc + phi * iv[3*i + l];
        v[3*i + l] = vn;
        x[3*i + l] += vn;
    }
}

// ---------------- pack outputs: [x(30000), h(640000), v(30000)] ----------------
__global__ void out_kernel(const float* __restrict__ x, const float* __restrict__ h,
                           const float* __restrict__ v, float* __restrict__ out) {
    int j = blockIdx.x * blockDim.x + threadIdx.x;
    const int nx = 3*N_NODES, nh = HID*N_NODES;
    if (j >= nx + nh + nx) return;
    if (j < nx) out[j] = x[j];
    else if (j < nx + nh) out[j] = h[j - nx];
    else out[j] = v[j - nx - nh];
}

extern "C" void kernel_launch(void* const* d_in, const int* in_sizes, int n_in,
                              void* d_out, int out_size, void* d_ws, size_t ws_size,
                              hipStream_t stream) {
    const float* his   = (const float*)d_in[0];
    const float* loc   = (const float*)d_in[1];
    const int*   edges = (const int*)  d_in[2];
    const float* vel   = (const float*)d_in[3];
    const float* eattr = (const float*)d_in[4];
    const float* emb_w = (const float*)d_in[5];
    const float* emb_b = (const float*)d_in[6];
    const float* ew1 = (const float*)d_in[7];
    const float* eb1 = (const float*)d_in[8];
    const float* ew2 = (const float*)d_in[9];
    const float* eb2 = (const float*)d_in[10];
    const float* nw1 = (const float*)d_in[11];
    const float* nb1 = (const float*)d_in[12];
    const float* nw2 = (const float*)d_in[13];
    const float* nb2 = (const float*)d_in[14];
    const float* cw1 = (const float*)d_in[15];
    const float* cb1 = (const float*)d_in[16];
    const float* cw2 = (const float*)d_in[17];
    const float* vw1 = (const float*)d_in[18];
    const float* vb1 = (const float*)d_in[19];
    const float* vw2 = (const float*)d_in[20];
    const float* vb2 = (const float*)d_in[21];

    const int* erow = edges;
    const int* ecol = edges + N_EDGES;

    char* ws = (char*)d_ws;
    size_t off = 0;
    auto walloc = [&](size_t bytes) -> void* {
        void* p = ws + off; off += (bytes + 255) & ~(size_t)255; return p;
    };
    float* h_a  = (float*)walloc((size_t)N_NODES*HID*4);
    float* h_b  = (float*)walloc((size_t)N_NODES*HID*4);
    float* xb   = (float*)walloc((size_t)N_NODES*3*4);
    float* vb   = (float*)walloc((size_t)N_NODES*3*4);
    float* ivb  = (float*)walloc((size_t)N_NODES*3*4);
    float* efb  = (float*)walloc((size_t)N_EDGES*HID*4);
    float* cgb  = (float*)walloc((size_t)N_EDGES*3*4);
    int* counts = (int*)walloc((size_t)N_NODES*4);
    int* cursor = (int*)walloc((size_t)N_NODES*4);
    int* offs   = (int*)walloc((size_t)(N_NODES+1)*4);
    int* elist  = (int*)walloc((size_t)N_EDGES*4);

    (void)hipMemsetAsync(counts, 0, (size_t)N_NODES*4, stream);
    (void)hipMemsetAsync(cursor, 0, (size_t)N_NODES*4, stream);

    init_kernel<<<(N_NODES+255)/256, 256, 0, stream>>>(loc, vel, xb, vb, ivb);
    embed_kernel<<<N_NODES, 64, 0, stream>>>(his, emb_w, emb_b, h_a);
    count_kernel<<<(N_EDGES+255)/256, 256, 0, stream>>>(erow, counts);
    scan_kernel<<<1, 1024, 0, stream>>>(counts, offs);
    scatter_kernel<<<(N_EDGES+255)/256, 256, 0, stream>>>(erow, offs, cursor, elist);

    float* h_cur = h_a;
    float* h_nxt = h_b;
    for (int layer = 0; layer < N_LAYERS; ++layer) {
        edge_kernel<<<512, 256, 0, stream>>>(h_cur, xb, erow, ecol, eattr,
                                             ew1, eb1, ew2, eb2, cw1, cb1, cw2,
                                             efb, cgb);
        node_kernel<<<N_NODES, 64, 0, stream>>>(h_cur, h_nxt, xb, vb, ivb, efb, cgb,
                                                offs, elist, nw1, nb1, nw2, nb2,
                                                vw1, vb1, vw2, vb2);
        float* tmp = h_cur; h_cur = h_nxt; h_nxt = tmp;
    }
    const int total = 3*N_NODES + HID*N_NODES + 3*N_NODES;
    out_kernel<<<(total+255)/256, 256, 0, stream>>>(xb, h_cur, vb, (float*)d_out);
}

// Round 3
// 600.219 us; speedup vs baseline: 4.8270x; 4.8270x over previous
//
#include <hip/hip_runtime.h>
#include <math.h>

#define N_NODES 10000
#define N_EDGES 320000
#define HID 64
#define N_LAYERS 4
#define EDGE_BLOCKS 1250          /* 1250 blocks * 4 waves * 4 tiles * 16 edges = 320000 */
#define TILES_PER_WAVE 4

typedef unsigned short ushort_t;
typedef unsigned int uint_t;
typedef __attribute__((ext_vector_type(8))) short short8;
typedef __attribute__((ext_vector_type(4))) float floatx4;

__device__ __forceinline__ float silu_f(float x) {
    return x * (1.0f / (1.0f + __expf(-x)));
}
__device__ __forceinline__ ushort_t f2bf(float f) {
    uint_t u = __float_as_uint(f);
    uint_t r = u + 0x7FFFu + ((u >> 16) & 1u);   // RNE
    return (ushort_t)(r >> 16);
}
__device__ __forceinline__ float bf2f(ushort_t u) {
    return __uint_as_float(((uint_t)u) << 16);
}

// ---------------- init: copy x,v + normalized init vel ----------------
__global__ void init_kernel(const float* __restrict__ loc, const float* __restrict__ vel,
                            float* __restrict__ x, float* __restrict__ v, float* __restrict__ iv) {
    int i = blockIdx.x * blockDim.x + threadIdx.x;
    if (i >= N_NODES) return;
    float v0 = vel[3*i], v1 = vel[3*i+1], v2 = vel[3*i+2];
    float nrm = sqrtf(v0*v0 + v1*v1 + v2*v2) + 1e-8f;
    x[3*i] = loc[3*i]; x[3*i+1] = loc[3*i+1]; x[3*i+2] = loc[3*i+2];
    v[3*i] = v0; v[3*i+1] = v1; v[3*i+2] = v2;
    iv[3*i] = v0/nrm; iv[3*i+1] = v1/nrm; iv[3*i+2] = v2/nrm;
}

// ---------------- embedding: h0 = his @ emb_w + emb_b (+ bf16 copy) ----------------
__global__ __launch_bounds__(64) void embed_kernel(const float* __restrict__ his,
                                                   const float* __restrict__ w,
                                                   const float* __restrict__ b,
                                                   float* __restrict__ h0,
                                                   ushort_t* __restrict__ hbf) {
    int i = blockIdx.x, l = threadIdx.x;
    float acc = b[l];
    #pragma unroll
    for (int k = 0; k < 4; ++k) acc += his[i*4+k] * w[k*HID+l];
    h0[i*HID+l] = acc;
    hbf[i*HID+l] = f2bf(acc);
}

// ---------------- CSR build ----------------
__global__ void count_kernel(const int* __restrict__ erow, int* __restrict__ counts) {
    int e = blockIdx.x * blockDim.x + threadIdx.x;
    if (e < N_EDGES) atomicAdd(&counts[erow[e]], 1);
}

__global__ __launch_bounds__(1024) void scan_kernel(const int* __restrict__ counts,
                                                    int* __restrict__ offs) {
    __shared__ int sd[1024];
    __shared__ int running;
    if (threadIdx.x == 0) { running = 0; offs[0] = 0; }
    __syncthreads();
    for (int base = 0; base < N_NODES; base += 1024) {
        int i = base + threadIdx.x;
        int val = (i < N_NODES) ? counts[i] : 0;
        sd[threadIdx.x] = val;
        __syncthreads();
        for (int d = 1; d < 1024; d <<= 1) {
            int tmp = (threadIdx.x >= d) ? sd[threadIdx.x - d] : 0;
            __syncthreads();
            sd[threadIdx.x] += tmp;
            __syncthreads();
        }
        if (i < N_NODES) offs[i+1] = running + sd[threadIdx.x];
        __syncthreads();
        if (threadIdx.x == 0) running += sd[1023];
        __syncthreads();
    }
}

__global__ void scatter_kernel(const int* __restrict__ erow, const int* __restrict__ offs,
                               int* __restrict__ cursor, int* __restrict__ elist) {
    int e = blockIdx.x * blockDim.x + threadIdx.x;
    if (e < N_EDGES) {
        int r = erow[e];
        int p = atomicAdd(&cursor[r], 1);
        elist[offs[r] + p] = e;
    }
}

// ---------------- weight pack: per-lane MFMA B-fragment order, bf16 ----------------
// B[k][n] fragment for lane: n = 16*nt + (lane&15), k = 32*kt + (lane>>4)*8 + j
__global__ void pack_weights(const float* __restrict__ ew1, const float* __restrict__ ew2,
                             const float* __restrict__ cw1,
                             ushort_t* __restrict__ pw1, ushort_t* __restrict__ pw2,
                             ushort_t* __restrict__ pc1) {
    int t = blockIdx.x * blockDim.x + threadIdx.x;   // 2048 total
    if (t < 1024) {                                  // W1: kt 0..3
        int kt = t >> 8, nt = (t >> 6) & 3, lane = t & 63;
        int quad = lane >> 4, lo = lane & 15;
        #pragma unroll
        for (int j = 0; j < 8; ++j) {
            int k = 32*kt + quad*8 + j, n = 16*nt + lo;
            pw1[(size_t)t*8 + j] = f2bf(ew1[k*HID + n]);
        }
    } else if (t < 1536) {                           // W2: kt 0..1
        int t2 = t - 1024;
        int kt = t2 >> 8, nt = (t2 >> 6) & 3, lane = t2 & 63;
        int quad = lane >> 4, lo = lane & 15;
        #pragma unroll
        for (int j = 0; j < 8; ++j) {
            int k = 32*kt + quad*8 + j, n = 16*nt + lo;
            pw2[(size_t)t2*8 + j] = f2bf(ew2[k*HID + n]);
        }
    } else if (t < 2048) {                           // CW1: kt 0..1
        int t3 = t - 1536;
        int kt = t3 >> 8, nt = (t3 >> 6) & 3, lane = t3 & 63;
        int quad = lane >> 4, lo = lane & 15;
        #pragma unroll
        for (int j = 0; j < 8; ++j) {
            int k = 32*kt + quad*8 + j, n = 16*nt + lo;
            pc1[(size_t)t3*8 + j] = f2bf(cw1[k*HID + n]);
        }
    }
}

// ---------------- MFMA edge kernel: 16 edges per wave-tile ----------------
__global__ __launch_bounds__(256) void edge_kernel(
    const ushort_t* __restrict__ hbf, const float* __restrict__ x,
    const int* __restrict__ erow, const int* __restrict__ ecol,
    const float* __restrict__ eattr,
    const float* __restrict__ ew1,   // ragged rows 128..130 (f32)
    const float* __restrict__ eb1, const float* __restrict__ eb2,
    const float* __restrict__ cb1, const float* __restrict__ cw2,
    const ushort_t* __restrict__ pw1, const ushort_t* __restrict__ pw2,
    const ushort_t* __restrict__ pc1,
    ushort_t* __restrict__ ef_out, float* __restrict__ cg_out)
{
    __shared__ ushort_t sW1[4*4*64*8];   // 16 KB
    __shared__ ushort_t sW2[2*4*64*8];   // 8 KB
    __shared__ ushort_t sC1[2*4*64*8];   // 8 KB
    __shared__ float sRW[3][HID];        // W1 rows 128..130 (radial, a0, a1)
    __shared__ float sB1[HID], sB2[HID], sCB1[HID], sCW2[HID];
    __shared__ ushort_t sAct[4][16*72];  // per-wave A round-trip (pad LD=72)
    __shared__ float sEdge[4][16][8];    // d0,d1,d2,radial,a0,a1,gate,pad

    for (int i = threadIdx.x; i < 4*4*64*8; i += 256) sW1[i] = pw1[i];
    for (int i = threadIdx.x; i < 2*4*64*8; i += 256) { sW2[i] = pw2[i]; sC1[i] = pc1[i]; }
    for (int i = threadIdx.x; i < 3*HID; i += 256) sRW[i/HID][i%HID] = ew1[(128 + i/HID)*HID + (i%HID)];
    if (threadIdx.x < HID) {
        sB1[threadIdx.x]  = eb1[threadIdx.x];
        sB2[threadIdx.x]  = eb2[threadIdx.x];
        sCB1[threadIdx.x] = cb1[threadIdx.x];
        sCW2[threadIdx.x] = cw2[threadIdx.x];
    }
    __syncthreads();

    const int wave = threadIdx.x >> 6, lane = threadIdx.x & 63;
    const int quad = lane >> 4, lo = lane & 15;
    ushort_t* act = sAct[wave];
    float (*sed)[8] = sEdge[wave];

    int tile = blockIdx.x * 4 + wave;
    for (int it = 0; it < TILES_PER_WAVE; ++it, tile += EDGE_BLOCKS*4) {
        const int e0 = tile * 16;
        // per-edge geometry (lanes 0..15)
        if (lane < 16) {
            int e = e0 + lane;
            int r = erow[e], c = ecol[e];
            float d0 = x[3*r]   - x[3*c];
            float d1 = x[3*r+1] - x[3*c+1];
            float d2 = x[3*r+2] - x[3*c+2];
            sed[lane][0] = d0; sed[lane][1] = d1; sed[lane][2] = d2;
            sed[lane][3] = d0*d0 + d1*d1 + d2*d2;
            sed[lane][4] = eattr[2*e]; sed[lane][5] = eattr[2*e+1];
        }
        // A-fragments for W1: A[m=lo][k] = h[r_m][k] (k<64), h[c_m][k-64]
        const int rme = erow[e0 + lo], cme = ecol[e0 + lo];
        const ushort_t* hr = hbf + (size_t)rme * HID;
        const ushort_t* hc = hbf + (size_t)cme * HID;
        short8 af0 = *(const short8*)(hr + quad*8);
        short8 af1 = *(const short8*)(hr + 32 + quad*8);
        short8 af2 = *(const short8*)(hc + quad*8);
        short8 af3 = *(const short8*)(hc + 32 + quad*8);
        __syncthreads();   // S1: sed visible

        // ---- GEMM1: [16x128] @ W1[128x64]
        floatx4 acc[4];
        #pragma unroll
        for (int nt = 0; nt < 4; ++nt) {
            floatx4 a = {0.f, 0.f, 0.f, 0.f};
            a = __builtin_amdgcn_mfma_f32_16x16x32_bf16(af0, *(const short8*)(sW1 + ((0*4+nt)*64+lane)*8), a, 0, 0, 0);
            a = __builtin_amdgcn_mfma_f32_16x16x32_bf16(af1, *(const short8*)(sW1 + ((1*4+nt)*64+lane)*8), a, 0, 0, 0);
            a = __builtin_amdgcn_mfma_f32_16x16x32_bf16(af2, *(const short8*)(sW1 + ((2*4+nt)*64+lane)*8), a, 0, 0, 0);
            a = __builtin_amdgcn_mfma_f32_16x16x32_bf16(af3, *(const short8*)(sW1 + ((3*4+nt)*64+lane)*8), a, 0, 0, 0);
            acc[nt] = a;
        }
        // ragged K (radial, a0, a1 in f32) + bias + silu -> f1 into act LDS
        #pragma unroll
        for (int nt = 0; nt < 4; ++nt) {
            const int n = 16*nt + lo;
            const float w128 = sRW[0][n], w129 = sRW[1][n], w130 = sRW[2][n], b1 = sB1[n];
            #pragma unroll
            for (int r = 0; r < 4; ++r) {
                const int m = 4*quad + r;
                float v = acc[nt][r] + sed[m][3]*w128 + sed[m][4]*w129 + sed[m][5]*w130 + b1;
                act[m*72 + n] = f2bf(silu_f(v));
            }
        }
        __syncthreads();   // S2

        // ---- GEMM2: f1[16x64] @ W2[64x64]
        short8 g0 = *(const short8*)(act + lo*72 + quad*8);
        short8 g1 = *(const short8*)(act + lo*72 + 32 + quad*8);
        floatx4 acc2[4];
        #pragma unroll
        for (int nt = 0; nt < 4; ++nt) {
            floatx4 a = {0.f, 0.f, 0.f, 0.f};
            a = __builtin_amdgcn_mfma_f32_16x16x32_bf16(g0, *(const short8*)(sW2 + ((0*4+nt)*64+lane)*8), a, 0, 0, 0);
            a = __builtin_amdgcn_mfma_f32_16x16x32_bf16(g1, *(const short8*)(sW2 + ((1*4+nt)*64+lane)*8), a, 0, 0, 0);
            acc2[nt] = a;
        }
        __syncthreads();   // S3: everyone done reading f1 before overwrite
        #pragma unroll
        for (int nt = 0; nt < 4; ++nt) {
            const int n = 16*nt + lo;
            const float b2 = sB2[n];
            #pragma unroll
            for (int r = 0; r < 4; ++r) {
                const int m = 4*quad + r;
                ushort_t efb = f2bf(silu_f(acc2[nt][r] + b2));
                ef_out[(size_t)(e0 + m)*HID + n] = efb;
                act[m*72 + n] = efb;
            }
        }
        __syncthreads();   // S4

        // ---- GEMM3: ef[16x64] @ CW1[64x64] -> silu -> dot cw2 -> gate[16]
        short8 q0 = *(const short8*)(act + lo*72 + quad*8);
        short8 q1 = *(const short8*)(act + lo*72 + 32 + quad*8);
        float gs[4] = {0.f, 0.f, 0.f, 0.f};
        #pragma unroll
        for (int nt = 0; nt < 4; ++nt) {
            floatx4 a = {0.f, 0.f, 0.f, 0.f};
            a = __builtin_amdgcn_mfma_f32_16x16x32_bf16(q0, *(const short8*)(sC1 + ((0*4+nt)*64+lane)*8), a, 0, 0, 0);
            a = __builtin_amdgcn_mfma_f32_16x16x32_bf16(q1, *(const short8*)(sC1 + ((1*4+nt)*64+lane)*8), a, 0, 0, 0);
            const int n = 16*nt + lo;
            const float cb = sCB1[n], cw = sCW2[n];
            #pragma unroll
            for (int r = 0; r < 4; ++r) gs[r] += silu_f(a[r] + cb) * cw;
        }
        #pragma unroll
        for (int off = 1; off < 16; off <<= 1) {
            #pragma unroll
            for (int r = 0; r < 4; ++r) gs[r] += __shfl_xor(gs[r], off, 64);
        }
        if (lo == 0) {
            #pragma unroll
            for (int r = 0; r < 4; ++r) sed[4*quad + r][6] = gs[r];
        }
        __syncthreads();   // S5
        if (lane < 48) {
            const int es = lane / 3, d = lane - es*3;
            cg_out[(size_t)(e0 + es)*3 + d] = sed[es][d] * sed[es][6];
        }
        __syncthreads();   // S6: protect sed for next tile
    }
}

// ---------------- node kernel: aggregate + vel/coord + node MLP ----------------
__global__ __launch_bounds__(64) void node_kernel(
    const float* __restrict__ h_in, float* __restrict__ h_out, ushort_t* __restrict__ hbf_out,
    float* __restrict__ x, float* __restrict__ v, const float* __restrict__ iv,
    const ushort_t* __restrict__ ef, const float* __restrict__ cg,
    const int* __restrict__ offs, const int* __restrict__ elist,
    const float* __restrict__ nw1, const float* __restrict__ nb1,
    const float* __restrict__ nw2, const float* __restrict__ nb2,
    const float* __restrict__ vw1, const float* __restrict__ vb1,
    const float* __restrict__ vw2, const float* __restrict__ vb2)
{
    const int i = blockIdx.x, l = threadIdx.x;
    __shared__ float sh[HID], sagg[HID], st1[HID];
    const float hl = h_in[(size_t)i*HID + l];
    sh[l] = hl;
    const int s = offs[i], t = offs[i+1];
    float aggl = 0.f, accl = 0.f;
    for (int p = s; p < t; ++p) {
        const int e = elist[p];
        aggl += bf2f(ef[(size_t)e*HID + l]);
        if (l < 3) accl += cg[(size_t)e*3 + l];
    }
    sagg[l] = aggl;
    __syncthreads();

    // phi = silu(h @ vw1 + vb1) @ vw2 + vb2
    float a = vb1[l];
    #pragma unroll 8
    for (int k = 0; k < HID; ++k) a += sh[k] * vw1[k*HID + l];
    float pl = silu_f(a) * vw2[l];
    #pragma unroll
    for (int d = 32; d > 0; d >>= 1) pl += __shfl_xor(pl, d, 64);
    const float phi = pl + vb2[0];

    // node MLP: silu([h, agg] @ nw1 + nb1) @ nw2 + nb2, residual add
    float b = nb1[l];
    #pragma unroll 8
    for (int k = 0; k < HID; ++k) b += sh[k]   * nw1[k*HID + l];
    #pragma unroll 8
    for (int k = 0; k < HID; ++k) b += sagg[k] * nw1[(HID+k)*HID + l];
    b = silu_f(b);
    st1[l] = b;
    __syncthreads();
    float cacc = nb2[l];
    #pragma unroll 8
    for (int k = 0; k < HID; ++k) cacc += st1[k] * nw2[k*HID + l];
    const float hnew = hl + cacc;
    h_out[(size_t)i*HID + l] = hnew;
    hbf_out[(size_t)i*HID + l] = f2bf(hnew);

    if (l < 3) {
        const int cnt = t - s;
        const float acc = accl / (float)(cnt > 0 ? cnt : 1);
        const float vn = v[3*i + l] + acc + phi * iv[3*i + l];
        v[3*i + l] = vn;
        x[3*i + l] += vn;
    }
}

// ---------------- pack outputs: [x(30000), h(640000), v(30000)] ----------------
__global__ void out_kernel(const float* __restrict__ x, const float* __restrict__ h,
                           const float* __restrict__ v, float* __restrict__ out) {
    int j = blockIdx.x * blockDim.x + threadIdx.x;
    const int nx = 3*N_NODES, nh = HID*N_NODES;
    if (j >= nx + nh + nx) return;
    if (j < nx) out[j] = x[j];
    else if (j < nx + nh) out[j] = h[j - nx];
    else out[j] = v[j - nx - nh];
}

extern "C" void kernel_launch(void* const* d_in, const int* in_sizes, int n_in,
                              void* d_out, int out_size, void* d_ws, size_t ws_size,
                              hipStream_t stream) {
    const float* his   = (const float*)d_in[0];
    const float* loc   = (const float*)d_in[1];
    const int*   edges = (const int*)  d_in[2];
    const float* vel   = (const float*)d_in[3];
    const float* eattr = (const float*)d_in[4];
    const float* emb_w = (const float*)d_in[5];
    const float* emb_b = (const float*)d_in[6];
    const float* ew1 = (const float*)d_in[7];
    const float* eb1 = (const float*)d_in[8];
    const float* ew2 = (const float*)d_in[9];
    const float* eb2 = (const float*)d_in[10];
    const float* nw1 = (const float*)d_in[11];
    const float* nb1 = (const float*)d_in[12];
    const float* nw2 = (const float*)d_in[13];
    const float* nb2 = (const float*)d_in[14];
    const float* cw1 = (const float*)d_in[15];
    const float* cb1 = (const float*)d_in[16];
    const float* cw2 = (const float*)d_in[17];
    const float* vw1 = (const float*)d_in[18];
    const float* vb1 = (const float*)d_in[19];
    const float* vw2 = (const float*)d_in[20];
    const float* vb2 = (const float*)d_in[21];

    const int* erow = edges;
    const int* ecol = edges + N_EDGES;

    char* ws = (char*)d_ws;
    size_t off = 0;
    auto walloc = [&](size_t bytes) -> void* {
        void* p = ws + off; off += (bytes + 255) & ~(size_t)255; return p;
    };
    float* h_a      = (float*)walloc((size_t)N_NODES*HID*4);
    float* h_b      = (float*)walloc((size_t)N_NODES*HID*4);
    ushort_t* hbf   = (ushort_t*)walloc((size_t)N_NODES*HID*2);
    float* xb       = (float*)walloc((size_t)N_NODES*3*4);
    float* vb       = (float*)walloc((size_t)N_NODES*3*4);
    float* ivb      = (float*)walloc((size_t)N_NODES*3*4);
    ushort_t* efbf  = (ushort_t*)walloc((size_t)N_EDGES*HID*2);
    float* cgb      = (float*)walloc((size_t)N_EDGES*3*4);
    int* counts     = (int*)walloc((size_t)N_NODES*4);
    int* cursor     = (int*)walloc((size_t)N_NODES*4);
    int* offs       = (int*)walloc((size_t)(N_NODES+1)*4);
    int* elist      = (int*)walloc((size_t)N_EDGES*4);
    ushort_t* pw1   = (ushort_t*)walloc((size_t)4*4*64*8*2);
    ushort_t* pw2   = (ushort_t*)walloc((size_t)2*4*64*8*2);
    ushort_t* pc1   = (ushort_t*)walloc((size_t)2*4*64*8*2);

    (void)hipMemsetAsync(counts, 0, (size_t)N_NODES*4, stream);
    (void)hipMemsetAsync(cursor, 0, (size_t)N_NODES*4, stream);

    init_kernel<<<(N_NODES+255)/256, 256, 0, stream>>>(loc, vel, xb, vb, ivb);
    embed_kernel<<<N_NODES, 64, 0, stream>>>(his, emb_w, emb_b, h_a, hbf);
    count_kernel<<<(N_EDGES+255)/256, 256, 0, stream>>>(erow, counts);
    scan_kernel<<<1, 1024, 0, stream>>>(counts, offs);
    scatter_kernel<<<(N_EDGES+255)/256, 256, 0, stream>>>(erow, offs, cursor, elist);
    pack_weights<<<8, 256, 0, stream>>>(ew1, ew2, cw1, pw1, pw2, pc1);

    float* h_cur = h_a;
    float* h_nxt = h_b;
    for (int layer = 0; layer < N_LAYERS; ++layer) {
        edge_kernel<<<EDGE_BLOCKS, 256, 0, stream>>>(hbf, xb, erow, ecol, eattr,
                                                     ew1, eb1, eb2, cb1, cw2,
                                                     pw1, pw2, pc1, efbf, cgb);
        node_kernel<<<N_NODES, 64, 0, stream>>>(h_cur, h_nxt, hbf, xb, vb, ivb, efbf, cgb,
                                                offs, elist, nw1, nb1, nw2, nb2,
                                                vw1, vb1, vw2, vb2);
        float* tmp = h_cur; h_cur = h_nxt; h_nxt = tmp;
    }
    const int total = 3*N_NODES + HID*N_NODES + 3*N_NODES;
    out_kernel<<<(total+255)/256, 256, 0, stream>>>(xb, h_cur, vb, (float*)d_out);
}